// Round 1
// baseline (4375.203 us; speedup 1.0000x reference)
//
#include <hip/hip_runtime.h>
#include <hip/hip_bf16.h>

#define NNODES 100000
#define NEDGES 2500000
#define CIN 32
#define CHID 16
#define COUT 64
#define NGRAPH 64

// ---------------- workspace layout (in floats, 64-float aligned) -------------
// [0, 100032)            deg   (int, zeroed)
// [100032, 1700032)      agg1  (N*16 f32, zeroed)
// [1700032, 3300032)     agg2  (N*16 f32, zeroed)
// [3300032, 4900032)     xl    (N*16)
// [4900032, 6500032)     xr    (N*16)
// [6500032, 8100032)     h     (N*16)
// [8100032, 14500032)    h2    (N*64)
#define OFF_DEG   0
#define OFF_AGG1  100032
#define OFF_AGG2  1700032
#define OFF_XL    3300032
#define OFF_XR    4900032
#define OFF_H     6500032
#define OFF_H2    8100032
#define ZERO_FLOATS 3300032  // deg + agg1 + agg2

__global__ __launch_bounds__(256) void deg_kernel(const int* __restrict__ dst,
                                                  int* __restrict__ deg) {
    int e = blockIdx.x * 256 + threadIdx.x;
    if (e < NEDGES) atomicAdd(&deg[dst[e]], 1);
}

// xl = x @ w1_l.T ; xr = x @ w1_r.T + b1   (per node, weights in LDS)
__global__ __launch_bounds__(256) void transform1(const float* __restrict__ x,
                                                  const float* __restrict__ w1l,
                                                  const float* __restrict__ b1,
                                                  const float* __restrict__ w1r,
                                                  float* __restrict__ xl,
                                                  float* __restrict__ xr) {
    __shared__ float wl[CHID * CIN];
    __shared__ float wr[CHID * CIN];
    __shared__ float bs[CHID];
    for (int i = threadIdx.x; i < CHID * CIN; i += 256) { wl[i] = w1l[i]; wr[i] = w1r[i]; }
    if (threadIdx.x < CHID) bs[threadIdx.x] = b1[threadIdx.x];
    __syncthreads();
    int n = blockIdx.x * 256 + threadIdx.x;
    if (n >= NNODES) return;
    float xv[CIN];
    const float4* x4 = (const float4*)(x + (size_t)n * CIN);
#pragma unroll
    for (int q = 0; q < CIN / 4; q++) {
        float4 v = x4[q];
        xv[4*q] = v.x; xv[4*q+1] = v.y; xv[4*q+2] = v.z; xv[4*q+3] = v.w;
    }
#pragma unroll
    for (int o = 0; o < CHID; o++) {
        float aL = 0.f, aR = bs[o];
#pragma unroll
        for (int i = 0; i < CIN; i++) {
            aL = fmaf(wl[o * CIN + i], xv[i], aL);
            aR = fmaf(wr[o * CIN + i], xv[i], aR);
        }
        xl[(size_t)n * CHID + o] = aL;
        xr[(size_t)n * CHID + o] = aR;
    }
}

// scatter-add 16-channel rows: agg[dst] += in[src]
__global__ __launch_bounds__(256) void edge_agg16(const int* __restrict__ src,
                                                  const int* __restrict__ dst,
                                                  const float* __restrict__ in,
                                                  float* __restrict__ agg) {
    int e = blockIdx.x * 256 + threadIdx.x;
    if (e >= NEDGES) return;
    int s = src[e], d = dst[e];
    const float4* r = (const float4*)(in + (size_t)s * CHID);
    float4 v0 = r[0], v1 = r[1], v2 = r[2], v3 = r[3];
    float* o = agg + (size_t)d * CHID;
    atomicAdd(o + 0,  v0.x); atomicAdd(o + 1,  v0.y);
    atomicAdd(o + 2,  v0.z); atomicAdd(o + 3,  v0.w);
    atomicAdd(o + 4,  v1.x); atomicAdd(o + 5,  v1.y);
    atomicAdd(o + 6,  v1.z); atomicAdd(o + 7,  v1.w);
    atomicAdd(o + 8,  v2.x); atomicAdd(o + 9,  v2.y);
    atomicAdd(o + 10, v2.z); atomicAdd(o + 11, v2.w);
    atomicAdd(o + 12, v3.x); atomicAdd(o + 13, v3.y);
    atomicAdd(o + 14, v3.z); atomicAdd(o + 15, v3.w);
}

// h = relu(agg1 / max(deg,1) + xr), vectorized float4 over N*16 floats
__global__ __launch_bounds__(256) void finalize1(const float* __restrict__ agg1,
                                                 const float* __restrict__ xr,
                                                 const int* __restrict__ deg,
                                                 float* __restrict__ h) {
    int t = blockIdx.x * 256 + threadIdx.x;  // one float4 per thread
    if (t >= NNODES * 4) return;
    int n = t >> 2;
    float inv = 1.0f / (float)max(deg[n], 1);
    float4 a = ((const float4*)agg1)[t];
    float4 b = ((const float4*)xr)[t];
    float4 r;
    r.x = fmaxf(fmaf(a.x, inv, b.x), 0.f);
    r.y = fmaxf(fmaf(a.y, inv, b.y), 0.f);
    r.z = fmaxf(fmaf(a.z, inv, b.z), 0.f);
    r.w = fmaxf(fmaf(a.w, inv, b.w), 0.f);
    ((float4*)h)[t] = r;
}

// per-node layer-2 output: h2[n] = (agg2[n]/deg) @ w2_l.T + b2 + h[n] @ w2_r.T
__global__ __launch_bounds__(256) void node_out(const float* __restrict__ agg2,
                                                const float* __restrict__ h,
                                                const int* __restrict__ deg,
                                                const float* __restrict__ w2l,
                                                const float* __restrict__ b2,
                                                const float* __restrict__ w2r,
                                                float* __restrict__ h2) {
    __shared__ float wl[COUT * CHID];
    __shared__ float wr[COUT * CHID];
    __shared__ float bs[COUT];
    for (int i = threadIdx.x; i < COUT * CHID; i += 256) { wl[i] = w2l[i]; wr[i] = w2r[i]; }
    if (threadIdx.x < COUT) bs[threadIdx.x] = b2[threadIdx.x];
    __syncthreads();
    int n = blockIdx.x * 256 + threadIdx.x;
    if (n >= NNODES) return;
    float inv = 1.0f / (float)max(deg[n], 1);
    float a[CHID], hv[CHID];
    const float4* a4 = (const float4*)(agg2 + (size_t)n * CHID);
    const float4* h4 = (const float4*)(h + (size_t)n * CHID);
#pragma unroll
    for (int q = 0; q < CHID / 4; q++) {
        float4 va = a4[q], vh = h4[q];
        a[4*q] = va.x * inv; a[4*q+1] = va.y * inv; a[4*q+2] = va.z * inv; a[4*q+3] = va.w * inv;
        hv[4*q] = vh.x; hv[4*q+1] = vh.y; hv[4*q+2] = vh.z; hv[4*q+3] = vh.w;
    }
    float4* out4 = (float4*)(h2 + (size_t)n * COUT);
#pragma unroll
    for (int o4 = 0; o4 < COUT / 4; o4++) {
        float acc[4];
#pragma unroll
        for (int j = 0; j < 4; j++) {
            int o = o4 * 4 + j;
            float s = bs[o];
#pragma unroll
            for (int i = 0; i < CHID; i++) {
                s = fmaf(wl[o * CHID + i], a[i], s);
                s = fmaf(wr[o * CHID + i], hv[i], s);
            }
            acc[j] = s;
        }
        float4 v; v.x = acc[0]; v.y = acc[1]; v.z = acc[2]; v.w = acc[3];
        out4[o4] = v;
    }
}

__device__ inline int lower_bound_i(const int* __restrict__ b, int n, int key) {
    int lo = 0, hi = n;
    while (lo < hi) {
        int m = (lo + hi) >> 1;
        if (b[m] < key) lo = m + 1; else hi = m;
    }
    return lo;
}

// one block per graph; batch is sorted so node range is contiguous
__global__ __launch_bounds__(256) void pool_kernel(const float* __restrict__ h2,
                                                   const int* __restrict__ batch,
                                                   float* __restrict__ out) {
    __shared__ float red[4 * COUT];
    int g = blockIdx.x;
    int start = lower_bound_i(batch, NNODES, g);
    int end = lower_bound_i(batch, NNODES, g + 1);
    int cnt = end - start;
    int r = threadIdx.x >> 6;   // 0..3
    int c = threadIdx.x & 63;   // channel
    float sum = 0.f;
    for (int n = start + r; n < end; n += 4) sum += h2[(size_t)n * COUT + c];
    red[r * COUT + c] = sum;
    __syncthreads();
    if (r == 0) {
        float tot = red[c] + red[COUT + c] + red[2 * COUT + c] + red[3 * COUT + c];
        out[g * COUT + c] = tot / (float)max(cnt, 1);
    }
}

extern "C" void kernel_launch(void* const* d_in, const int* in_sizes, int n_in,
                              void* d_out, int out_size, void* d_ws, size_t ws_size,
                              hipStream_t stream) {
    const float* x    = (const float*)d_in[0];
    const int*   ei   = (const int*)d_in[1];   // [2, E] int32
    const int*   batch= (const int*)d_in[2];
    const float* w1l  = (const float*)d_in[3];
    const float* b1   = (const float*)d_in[4];
    const float* w1r  = (const float*)d_in[5];
    const float* w2l  = (const float*)d_in[6];
    const float* b2   = (const float*)d_in[7];
    const float* w2r  = (const float*)d_in[8];
    float* out = (float*)d_out;

    const int* src = ei;
    const int* dst = ei + NEDGES;

    float* ws   = (float*)d_ws;
    int*   deg  = (int*)(ws + OFF_DEG);
    float* agg1 = ws + OFF_AGG1;
    float* agg2 = ws + OFF_AGG2;
    float* xl   = ws + OFF_XL;
    float* xr   = ws + OFF_XR;
    float* h    = ws + OFF_H;
    float* h2   = ws + OFF_H2;

    hipMemsetAsync(d_ws, 0, (size_t)ZERO_FLOATS * sizeof(float), stream);

    int ebl = (NEDGES + 255) / 256;
    int nbl = (NNODES + 255) / 256;

    deg_kernel<<<ebl, 256, 0, stream>>>(dst, deg);
    transform1<<<nbl, 256, 0, stream>>>(x, w1l, b1, w1r, xl, xr);
    edge_agg16<<<ebl, 256, 0, stream>>>(src, dst, xl, agg1);
    finalize1<<<(NNODES * 4 + 255) / 256, 256, 0, stream>>>(agg1, xr, deg, h);
    edge_agg16<<<ebl, 256, 0, stream>>>(src, dst, h, agg2);
    node_out<<<nbl, 256, 0, stream>>>(agg2, h, deg, w2l, b2, w2r, h2);
    pool_kernel<<<NGRAPH, 256, 0, stream>>>(h2, batch, out);
}

// Round 2
// 640.074 us; speedup vs baseline: 6.8355x; 6.8355x over previous
//
#include <hip/hip_runtime.h>
#include <hip/hip_bf16.h>

#define NNODES 100000
#define NEDGES 2500000
#define CIN 32
#define CHID 16
#define COUT 64
#define NGRAPH 64

#define NBLK_SCAN 391          // ceil(100000/256)

// ---------------- workspace layout (4-byte units) ----------------------------
// deg     [0,       100352)   int, zeroed by memset
// offs    [100352,  200448)   int (100001 used)
// cursor  [200448,  300800)   int
// bsum    [300800,  301312)   int
// csr     [301312, 2801344)   int (2.5M src ids, sorted by dst)
// xl      [2801344, 4401344)  f32 N*16
// xr      [4401344, 6001344)  f32 N*16
// h       [6001344, 7601344)  f32 N*16
// h2      [7601344,14001344)  f32 N*64     => 56.0 MB total
#define OFF_DEG   0
#define OFF_OFFS  100352
#define OFF_CUR   200448
#define OFF_BSUM  300800
#define OFF_CSR   301312
#define OFF_XL    2801344
#define OFF_XR    4401344
#define OFF_H     6001344
#define OFF_H2    7601344

__global__ __launch_bounds__(256) void count_deg(const int* __restrict__ dst,
                                                 int* __restrict__ deg) {
    int e = blockIdx.x * 256 + threadIdx.x;
    if (e < NEDGES) atomicAdd(&deg[dst[e]], 1);
}

// block-local exclusive scan of deg -> offs (partial), block totals -> bsum
__global__ __launch_bounds__(256) void scan1(const int* __restrict__ deg,
                                             int* __restrict__ offs,
                                             int* __restrict__ bsum) {
    __shared__ int tmp[256];
    int i = blockIdx.x * 256 + threadIdx.x;
    int v = (i < NNODES) ? deg[i] : 0;
    tmp[threadIdx.x] = v;
    __syncthreads();
#pragma unroll
    for (int d = 1; d < 256; d <<= 1) {
        int t = (threadIdx.x >= d) ? tmp[threadIdx.x - d] : 0;
        __syncthreads();
        tmp[threadIdx.x] += t;
        __syncthreads();
    }
    if (i < NNODES) offs[i] = tmp[threadIdx.x] - v;   // exclusive
    if (threadIdx.x == 255) bsum[blockIdx.x] = tmp[255];
}

// single-block exclusive scan of the 391 block sums
__global__ __launch_bounds__(512) void scan2(int* __restrict__ bsum) {
    __shared__ int tmp[512];
    int t = threadIdx.x;
    int v = (t < NBLK_SCAN) ? bsum[t] : 0;
    tmp[t] = v;
    __syncthreads();
#pragma unroll
    for (int d = 1; d < 512; d <<= 1) {
        int u = (t >= d) ? tmp[t - d] : 0;
        __syncthreads();
        tmp[t] += u;
        __syncthreads();
    }
    if (t < NBLK_SCAN) bsum[t] = tmp[t] - v;          // exclusive
}

// add block offsets; init cursor; offs[NNODES] = NEDGES
__global__ __launch_bounds__(256) void scan3(int* __restrict__ offs,
                                             int* __restrict__ cursor,
                                             const int* __restrict__ bsum) {
    int i = blockIdx.x * 256 + threadIdx.x;
    if (i < NNODES) {
        int o = offs[i] + bsum[blockIdx.x];
        offs[i] = o;
        cursor[i] = o;
    }
    if (i == 0) offs[NNODES] = NEDGES;
}

// scatter src ids into CSR slots (sorted by dst)
__global__ __launch_bounds__(256) void scatter_csr(const int* __restrict__ src,
                                                   const int* __restrict__ dst,
                                                   int* __restrict__ cursor,
                                                   int* __restrict__ csr) {
    int e = blockIdx.x * 256 + threadIdx.x;
    if (e >= NEDGES) return;
    int pos = atomicAdd(&cursor[dst[e]], 1);
    csr[pos] = src[e];
}

// xl = x @ w1_l.T ; xr = x @ w1_r.T + b1   (per node, weights in LDS)
__global__ __launch_bounds__(256) void transform1(const float* __restrict__ x,
                                                  const float* __restrict__ w1l,
                                                  const float* __restrict__ b1,
                                                  const float* __restrict__ w1r,
                                                  float* __restrict__ xl,
                                                  float* __restrict__ xr) {
    __shared__ float wl[CHID * CIN];
    __shared__ float wr[CHID * CIN];
    __shared__ float bs[CHID];
    for (int i = threadIdx.x; i < CHID * CIN; i += 256) { wl[i] = w1l[i]; wr[i] = w1r[i]; }
    if (threadIdx.x < CHID) bs[threadIdx.x] = b1[threadIdx.x];
    __syncthreads();
    int n = blockIdx.x * 256 + threadIdx.x;
    if (n >= NNODES) return;
    float xv[CIN];
    const float4* x4 = (const float4*)(x + (size_t)n * CIN);
#pragma unroll
    for (int q = 0; q < CIN / 4; q++) {
        float4 v = x4[q];
        xv[4*q] = v.x; xv[4*q+1] = v.y; xv[4*q+2] = v.z; xv[4*q+3] = v.w;
    }
#pragma unroll
    for (int o = 0; o < CHID; o++) {
        float aL = 0.f, aR = bs[o];
#pragma unroll
        for (int i = 0; i < CIN; i++) {
            aL = fmaf(wl[o * CIN + i], xv[i], aL);
            aR = fmaf(wr[o * CIN + i], xv[i], aR);
        }
        xl[(size_t)n * CHID + o] = aL;
        xr[(size_t)n * CHID + o] = aR;
    }
}

// layer-1 aggregate + finalize: h[n] = relu(mean_{in-edges}(xl[src]) + xr[n])
// 16 lanes per node: lane c owns channel c. One coalesced 64B gather per edge.
__global__ __launch_bounds__(256) void agg1_fused(const int* __restrict__ offs,
                                                  const int* __restrict__ csr,
                                                  const float* __restrict__ xl,
                                                  const float* __restrict__ xr,
                                                  float* __restrict__ h) {
    int node = blockIdx.x * 16 + (threadIdx.x >> 4);
    int c = threadIdx.x & 15;
    if (node >= NNODES) return;
    int s0 = offs[node], s1 = offs[node + 1];
    float acc = 0.f;
    int p = s0;
    for (; p + 1 < s1; p += 2) {
        int sA = csr[p], sB = csr[p + 1];
        acc += xl[(size_t)sA * CHID + c];
        acc += xl[(size_t)sB * CHID + c];
    }
    if (p < s1) acc += xl[(size_t)csr[p] * CHID + c];
    float mean = acc / (float)max(s1 - s0, 1);
    h[(size_t)node * CHID + c] = fmaxf(mean + xr[(size_t)node * CHID + c], 0.f);
}

// layer-2 aggregate fused with output transform:
// h2[n] = mean_{in}(h[src]) @ w2_l.T + b2 + h[n] @ w2_r.T
__global__ __launch_bounds__(256) void agg2_fused(const int* __restrict__ offs,
                                                  const int* __restrict__ csr,
                                                  const float* __restrict__ h,
                                                  const float* __restrict__ w2l,
                                                  const float* __restrict__ b2,
                                                  const float* __restrict__ w2r,
                                                  float* __restrict__ h2) {
    __shared__ float wl[COUT * CHID];
    __shared__ float wr[COUT * CHID];
    __shared__ float bs[COUT];
    __shared__ float mean_s[16 * CHID];   // 16 groups x 16 channels
    for (int i = threadIdx.x; i < COUT * CHID; i += 256) { wl[i] = w2l[i]; wr[i] = w2r[i]; }
    if (threadIdx.x < COUT) bs[threadIdx.x] = b2[threadIdx.x];
    __syncthreads();

    int g = threadIdx.x >> 4;
    int c = threadIdx.x & 15;
    int node = blockIdx.x * 16 + g;       // grid sized so node < NNODES always

    int s0 = offs[node], s1 = offs[node + 1];
    float acc = 0.f;
    int p = s0;
    for (; p + 1 < s1; p += 2) {
        int sA = csr[p], sB = csr[p + 1];
        acc += h[(size_t)sA * CHID + c];
        acc += h[(size_t)sB * CHID + c];
    }
    if (p < s1) acc += h[(size_t)csr[p] * CHID + c];
    mean_s[g * CHID + c] = acc / (float)max(s1 - s0, 1);
    __syncthreads();

    // own h row + group mean from LDS
    float hv[CHID], m[CHID];
    const float4* h4 = (const float4*)(h + (size_t)node * CHID);
#pragma unroll
    for (int q = 0; q < CHID / 4; q++) {
        float4 v = h4[q];
        hv[4*q] = v.x; hv[4*q+1] = v.y; hv[4*q+2] = v.z; hv[4*q+3] = v.w;
    }
#pragma unroll
    for (int i = 0; i < CHID; i++) m[i] = mean_s[g * CHID + i];

    // lane c computes output channels c, c+16, c+32, c+48
#pragma unroll
    for (int k = 0; k < 4; k++) {
        int o = c + 16 * k;
        float s = bs[o];
#pragma unroll
        for (int i = 0; i < CHID; i++) {
            s = fmaf(wl[o * CHID + i], m[i], s);
            s = fmaf(wr[o * CHID + i], hv[i], s);
        }
        h2[(size_t)node * COUT + o] = s;
    }
}

__device__ inline int lower_bound_i(const int* __restrict__ b, int n, int key) {
    int lo = 0, hi = n;
    while (lo < hi) {
        int m = (lo + hi) >> 1;
        if (b[m] < key) lo = m + 1; else hi = m;
    }
    return lo;
}

// one block per graph; batch is sorted so node range is contiguous
__global__ __launch_bounds__(256) void pool_kernel(const float* __restrict__ h2,
                                                   const int* __restrict__ batch,
                                                   float* __restrict__ out) {
    __shared__ float red[4 * COUT];
    int g = blockIdx.x;
    int start = lower_bound_i(batch, NNODES, g);
    int end = lower_bound_i(batch, NNODES, g + 1);
    int cnt = end - start;
    int r = threadIdx.x >> 6;   // 0..3
    int c = threadIdx.x & 63;   // channel
    float sum = 0.f;
    for (int n = start + r; n < end; n += 4) sum += h2[(size_t)n * COUT + c];
    red[r * COUT + c] = sum;
    __syncthreads();
    if (r == 0) {
        float tot = red[c] + red[COUT + c] + red[2 * COUT + c] + red[3 * COUT + c];
        out[g * COUT + c] = tot / (float)max(cnt, 1);
    }
}

extern "C" void kernel_launch(void* const* d_in, const int* in_sizes, int n_in,
                              void* d_out, int out_size, void* d_ws, size_t ws_size,
                              hipStream_t stream) {
    const float* x    = (const float*)d_in[0];
    const int*   ei   = (const int*)d_in[1];   // [2, E] int32
    const int*   batch= (const int*)d_in[2];
    const float* w1l  = (const float*)d_in[3];
    const float* b1   = (const float*)d_in[4];
    const float* w1r  = (const float*)d_in[5];
    const float* w2l  = (const float*)d_in[6];
    const float* b2   = (const float*)d_in[7];
    const float* w2r  = (const float*)d_in[8];
    float* out = (float*)d_out;

    const int* src = ei;
    const int* dst = ei + NEDGES;

    int*   ws_i  = (int*)d_ws;
    float* ws_f  = (float*)d_ws;
    int*   deg   = ws_i + OFF_DEG;
    int*   offs  = ws_i + OFF_OFFS;
    int*   cursor= ws_i + OFF_CUR;
    int*   bsum  = ws_i + OFF_BSUM;
    int*   csr   = ws_i + OFF_CSR;
    float* xl    = ws_f + OFF_XL;
    float* xr    = ws_f + OFF_XR;
    float* h     = ws_f + OFF_H;
    float* h2    = ws_f + OFF_H2;

    hipMemsetAsync(deg, 0, 100352 * sizeof(int), stream);

    int ebl = (NEDGES + 255) / 256;
    int nbl = (NNODES + 255) / 256;
    int abl = NNODES / 16;      // 6250, exact

    count_deg  <<<ebl, 256, 0, stream>>>(dst, deg);
    scan1      <<<NBLK_SCAN, 256, 0, stream>>>(deg, offs, bsum);
    scan2      <<<1, 512, 0, stream>>>(bsum);
    scan3      <<<NBLK_SCAN, 256, 0, stream>>>(offs, cursor, bsum);
    scatter_csr<<<ebl, 256, 0, stream>>>(src, dst, cursor, csr);
    transform1 <<<nbl, 256, 0, stream>>>(x, w1l, b1, w1r, xl, xr);
    agg1_fused <<<abl, 256, 0, stream>>>(offs, csr, xl, xr, h);
    agg2_fused <<<abl, 256, 0, stream>>>(offs, csr, h, w2l, b2, w2r, h2);
    pool_kernel<<<NGRAPH, 256, 0, stream>>>(h2, batch, out);
}

// Round 3
// 418.100 us; speedup vs baseline: 10.4645x; 1.5309x over previous
//
#include <hip/hip_runtime.h>
#include <hip/hip_bf16.h>

#define NNODES 100000
#define NEDGES 2500000
#define CIN 32
#define CHID 16
#define COUT 64
#define NGRAPH 64

#define NODES_PER_BUCKET 128
#define NBUCKETS 782            // ceil(100000/128); last bucket has 32 nodes
#define BCAP 4096               // bucket capacity (mean 3197, sigma ~56 -> 16 sigma margin)

// ---------------- workspace layout (4-byte units) ----------------------------
// bcnt   [0, 12512)            int, one counter per 16 ints (line-padded), zeroed
// boff   [12512, 13312)        int
// offs   [13312, 113344)       int (100001 used)
// csr    [113344, 2613344)     int
// xl     [2613376, 4213376)    f32
// xr     [4213376, 5813376)    f32
// h      [5813376, 7413376)    f32
// ebuf   [7413376, 13819520)   int2[782*4096]  (25.6MB)
// h2     aliases ebuf region   f32 N*64 (ebuf dead after bucket_build)
// total 55.28 MB
#define OFF_BCNT  0
#define OFF_BOFF  12512
#define OFF_OFFS  13312
#define OFF_CSR   113344
#define OFF_XL    2613376
#define OFF_XR    4213376
#define OFF_H     5813376
#define OFF_EBUF  7413376
#define OFF_H2    7413376

// scatter edges into fixed-capacity dst-buckets; writes are sequential within
// each bucket -> full-line HBM writes instead of 64B partial-line thrash
__global__ __launch_bounds__(256) void bucket_scatter(const int* __restrict__ src,
                                                      const int* __restrict__ dst,
                                                      int* __restrict__ bcnt,
                                                      int2* __restrict__ ebuf) {
    int e = blockIdx.x * 256 + threadIdx.x;
    if (e >= NEDGES) return;
    int d = dst[e];
    int s = src[e];
    int b = d >> 7;                      // 128 nodes per bucket
    int pos = atomicAdd(&bcnt[b * 16], 1);
    ebuf[(size_t)b * BCAP + pos] = make_int2(s, d);
}

// exclusive scan of 782 bucket counts
__global__ __launch_bounds__(1024) void scan_boff(const int* __restrict__ bcnt,
                                                  int* __restrict__ boff) {
    __shared__ int tmp[1024];
    int t = threadIdx.x;
    int v = (t < NBUCKETS) ? bcnt[t * 16] : 0;
    tmp[t] = v;
    __syncthreads();
#pragma unroll
    for (int d = 1; d < 1024; d <<= 1) {
        int u = (t >= d) ? tmp[t - d] : 0;
        __syncthreads();
        tmp[t] += u;
        __syncthreads();
    }
    if (t < NBUCKETS) boff[t] = tmp[t] - v;
}

// one block per bucket: per-node degree count in LDS, LDS scan, emit offs and
// dst-sorted csr. All global writes confined to the bucket's contiguous range.
__global__ __launch_bounds__(256) void bucket_build(const int* __restrict__ bcnt,
                                                    const int* __restrict__ boff,
                                                    const int2* __restrict__ ebuf,
                                                    int* __restrict__ csr,
                                                    int* __restrict__ offs) {
    __shared__ int hist[NODES_PER_BUCKET];
    __shared__ int tmp[NODES_PER_BUCKET];
    int b = blockIdx.x, tid = threadIdx.x;
    int nodes0 = b << 7;
    int cnt = bcnt[b * 16];
    int base = boff[b];
    if (tid < NODES_PER_BUCKET) hist[tid] = 0;
    __syncthreads();
    const int2* eb = ebuf + (size_t)b * BCAP;
    for (int i = tid; i < cnt; i += 256) atomicAdd(&hist[eb[i].y - nodes0], 1);
    __syncthreads();
    if (tid < NODES_PER_BUCKET) tmp[tid] = hist[tid];
    __syncthreads();
#pragma unroll
    for (int d = 1; d < NODES_PER_BUCKET; d <<= 1) {
        int u = (tid < NODES_PER_BUCKET && tid >= d) ? tmp[tid - d] : 0;
        __syncthreads();
        if (tid < NODES_PER_BUCKET) tmp[tid] += u;
        __syncthreads();
    }
    int nloc = min(NODES_PER_BUCKET, NNODES - nodes0);
    if (tid < NODES_PER_BUCKET) {
        int excl = tmp[tid] - hist[tid];
        hist[tid] = excl;                 // hist becomes the running cursor
        if (tid < nloc) offs[nodes0 + tid] = base + excl;
    }
    if (b == NBUCKETS - 1 && tid == 0) offs[NNODES] = NEDGES;
    __syncthreads();
    for (int i = tid; i < cnt; i += 256) {
        int2 e = eb[i];
        int p = atomicAdd(&hist[e.y - nodes0], 1);
        csr[base + p] = e.x;
    }
}

// xl = x @ w1_l.T ; xr = x @ w1_r.T + b1   (per node, weights in LDS, uniform
// LDS addresses -> broadcast, no conflicts)
__global__ __launch_bounds__(256) void transform1(const float* __restrict__ x,
                                                  const float* __restrict__ w1l,
                                                  const float* __restrict__ b1,
                                                  const float* __restrict__ w1r,
                                                  float* __restrict__ xl,
                                                  float* __restrict__ xr) {
    __shared__ float wl[CHID * CIN];
    __shared__ float wr[CHID * CIN];
    __shared__ float bs[CHID];
    for (int i = threadIdx.x; i < CHID * CIN; i += 256) { wl[i] = w1l[i]; wr[i] = w1r[i]; }
    if (threadIdx.x < CHID) bs[threadIdx.x] = b1[threadIdx.x];
    __syncthreads();
    int n = blockIdx.x * 256 + threadIdx.x;
    if (n >= NNODES) return;
    float xv[CIN];
    const float4* x4 = (const float4*)(x + (size_t)n * CIN);
#pragma unroll
    for (int q = 0; q < CIN / 4; q++) {
        float4 v = x4[q];
        xv[4*q] = v.x; xv[4*q+1] = v.y; xv[4*q+2] = v.z; xv[4*q+3] = v.w;
    }
#pragma unroll
    for (int o = 0; o < CHID; o++) {
        float aL = 0.f, aR = bs[o];
#pragma unroll
        for (int i = 0; i < CIN; i++) {
            aL = fmaf(wl[o * CIN + i], xv[i], aL);
            aR = fmaf(wr[o * CIN + i], xv[i], aR);
        }
        xl[(size_t)n * CHID + o] = aL;
        xr[(size_t)n * CHID + o] = aR;
    }
}

// layer-1 aggregate + finalize: h[n] = relu(mean_in(xl[src]) + xr[n])
// 16 lanes per node, lane c owns channel c; 64B coalesced gather per edge
__global__ __launch_bounds__(256) void agg1_fused(const int* __restrict__ offs,
                                                  const int* __restrict__ csr,
                                                  const float* __restrict__ xl,
                                                  const float* __restrict__ xr,
                                                  float* __restrict__ h) {
    int node = blockIdx.x * 16 + (threadIdx.x >> 4);
    int c = threadIdx.x & 15;
    if (node >= NNODES) return;
    int s0 = offs[node], s1 = offs[node + 1];
    float acc = 0.f;
    int p = s0;
    for (; p + 1 < s1; p += 2) {
        int sA = csr[p], sB = csr[p + 1];
        acc += xl[(size_t)sA * CHID + c];
        acc += xl[(size_t)sB * CHID + c];
    }
    if (p < s1) acc += xl[(size_t)csr[p] * CHID + c];
    float mean = acc / (float)max(s1 - s0, 1);
    h[(size_t)node * CHID + c] = fmaxf(mean + xr[(size_t)node * CHID + c], 0.f);
}

// layer-2 aggregate fused with output transform:
// h2[n] = mean_in(h[src]) @ w2_l.T + b2 + h[n] @ w2_r.T
// weights stored TRANSPOSED in LDS: wlT[i*COUT+o] so lane-varying o is
// contiguous -> conflict-free (was 8-way conflicted in round 2: 9.6M conflicts)
__global__ __launch_bounds__(256) void agg2_fused(const int* __restrict__ offs,
                                                  const int* __restrict__ csr,
                                                  const float* __restrict__ h,
                                                  const float* __restrict__ w2l,
                                                  const float* __restrict__ b2,
                                                  const float* __restrict__ w2r,
                                                  float* __restrict__ h2) {
    __shared__ float wlT[CHID * COUT];
    __shared__ float wrT[CHID * COUT];
    __shared__ float bs[COUT];
    __shared__ float mean_s[16 * CHID];
    for (int idx = threadIdx.x; idx < CHID * COUT; idx += 256) {
        int i = idx >> 6, o = idx & 63;
        wlT[idx] = w2l[o * CHID + i];
        wrT[idx] = w2r[o * CHID + i];
    }
    if (threadIdx.x < COUT) bs[threadIdx.x] = b2[threadIdx.x];
    __syncthreads();

    int g = threadIdx.x >> 4;
    int c = threadIdx.x & 15;
    int node = blockIdx.x * 16 + g;       // grid exact: 6250*16 = 100000

    int s0 = offs[node], s1 = offs[node + 1];
    float acc = 0.f;
    int p = s0;
    for (; p + 1 < s1; p += 2) {
        int sA = csr[p], sB = csr[p + 1];
        acc += h[(size_t)sA * CHID + c];
        acc += h[(size_t)sB * CHID + c];
    }
    if (p < s1) acc += h[(size_t)csr[p] * CHID + c];
    mean_s[g * CHID + c] = acc / (float)max(s1 - s0, 1);
    __syncthreads();

    float hv[CHID], m[CHID];
    const float4* h4 = (const float4*)(h + (size_t)node * CHID);
#pragma unroll
    for (int q = 0; q < CHID / 4; q++) {
        float4 v = h4[q];
        hv[4*q] = v.x; hv[4*q+1] = v.y; hv[4*q+2] = v.z; hv[4*q+3] = v.w;
    }
#pragma unroll
    for (int i = 0; i < CHID; i++) m[i] = mean_s[g * CHID + i];

#pragma unroll
    for (int k = 0; k < 4; k++) {
        int o = c + 16 * k;
        float s = bs[o];
#pragma unroll
        for (int i = 0; i < CHID; i++) {
            s = fmaf(wlT[i * COUT + o], m[i], s);
            s = fmaf(wrT[i * COUT + o], hv[i], s);
        }
        h2[(size_t)node * COUT + o] = s;
    }
}

__device__ inline int lower_bound_i(const int* __restrict__ b, int n, int key) {
    int lo = 0, hi = n;
    while (lo < hi) {
        int m = (lo + hi) >> 1;
        if (b[m] < key) lo = m + 1; else hi = m;
    }
    return lo;
}

// 8 blocks per graph, partial sums -> f32 atomics into zeroed d_out
__global__ __launch_bounds__(256) void pool_kernel(const float* __restrict__ h2,
                                                   const int* __restrict__ batch,
                                                   float* __restrict__ out) {
    __shared__ float red[4 * COUT];
    int g = blockIdx.x >> 3;
    int part = blockIdx.x & 7;
    int start = lower_bound_i(batch, NNODES, g);
    int end = lower_bound_i(batch, NNODES, g + 1);
    int cnt = end - start;
    int r = threadIdx.x >> 6;   // 0..3
    int c = threadIdx.x & 63;   // channel
    float sum = 0.f;
    for (int n = start + part * 4 + r; n < end; n += 32) sum += h2[(size_t)n * COUT + c];
    red[r * COUT + c] = sum;
    __syncthreads();
    if (r == 0) {
        float tot = red[c] + red[COUT + c] + red[2 * COUT + c] + red[3 * COUT + c];
        atomicAdd(&out[g * COUT + c], tot / (float)max(cnt, 1));
    }
}

extern "C" void kernel_launch(void* const* d_in, const int* in_sizes, int n_in,
                              void* d_out, int out_size, void* d_ws, size_t ws_size,
                              hipStream_t stream) {
    const float* x    = (const float*)d_in[0];
    const int*   ei   = (const int*)d_in[1];   // [2, E] int32
    const int*   batch= (const int*)d_in[2];
    const float* w1l  = (const float*)d_in[3];
    const float* b1   = (const float*)d_in[4];
    const float* w1r  = (const float*)d_in[5];
    const float* w2l  = (const float*)d_in[6];
    const float* b2   = (const float*)d_in[7];
    const float* w2r  = (const float*)d_in[8];
    float* out = (float*)d_out;

    const int* src = ei;
    const int* dst = ei + NEDGES;

    int*   ws_i  = (int*)d_ws;
    float* ws_f  = (float*)d_ws;
    int*   bcnt  = ws_i + OFF_BCNT;
    int*   boff  = ws_i + OFF_BOFF;
    int*   offs  = ws_i + OFF_OFFS;
    int*   csr   = ws_i + OFF_CSR;
    float* xl    = ws_f + OFF_XL;
    float* xr    = ws_f + OFF_XR;
    float* h     = ws_f + OFF_H;
    int2*  ebuf  = (int2*)(ws_i + OFF_EBUF);
    float* h2    = ws_f + OFF_H2;           // aliases ebuf (dead after bucket_build)

    hipMemsetAsync(bcnt, 0, 12512 * sizeof(int), stream);
    hipMemsetAsync(out, 0, NGRAPH * COUT * sizeof(float), stream);

    int ebl = (NEDGES + 255) / 256;
    int nbl = (NNODES + 255) / 256;
    int abl = NNODES / 16;      // 6250, exact

    bucket_scatter<<<ebl, 256, 0, stream>>>(src, dst, bcnt, ebuf);
    scan_boff     <<<1, 1024, 0, stream>>>(bcnt, boff);
    bucket_build  <<<NBUCKETS, 256, 0, stream>>>(bcnt, boff, ebuf, csr, offs);
    transform1    <<<nbl, 256, 0, stream>>>(x, w1l, b1, w1r, xl, xr);
    agg1_fused    <<<abl, 256, 0, stream>>>(offs, csr, xl, xr, h);
    agg2_fused    <<<abl, 256, 0, stream>>>(offs, csr, h, w2l, b2, w2r, h2);
    pool_kernel   <<<NGRAPH * 8, 256, 0, stream>>>(h2, batch, out);
}

// Round 4
// 407.517 us; speedup vs baseline: 10.7362x; 1.0260x over previous
//
#include <hip/hip_runtime.h>
#include <hip/hip_bf16.h>

#define NNODES 100000
#define NEDGES 2500000
#define CIN 32
#define CHID 16
#define COUT 64
#define NGRAPH 64

#define NPB 128                 // nodes per bucket
#define NBUCKETS 782            // ceil(100000/128)
#define NSLOT 8                 // sub-bucket per XCD-class (blockIdx & 7)
#define CELLCAP 640             // per (bucket,slot): mean 400, sigma 20 -> 12 sigma

// ---------------- workspace layout (4-byte units) ----------------------------
// bcnt  [0, 25088)          int, (bucket*8+slot)*4 stride-4 padded, zeroed
// boff  [25088, 26112)      int
// ginv  [26112, 26176)      f32
// offs  [26176, 126208)     int (100001 used)
// csr   [126208, 2626208)   int
// ebuf  [2626240, 6630080)  int packed (src<<7)|dstloc, 782*8*640
// xl    [6630080, 8230080)  f32
// xr    [8230080, 9830080)  f32
// h     [9830080, 11430080) f32            => 45.7 MB total
#define OFF_BCNT  0
#define OFF_BOFF  25088
#define OFF_GINV  26112
#define OFF_OFFS  26176
#define OFF_CSR   126208
#define OFF_EBUF  2626240
#define OFF_XL    6630080
#define OFF_XR    8230080
#define OFF_H     9830080

// scatter edges into (bucket, blockIdx&7) cells. Slot-class ~ XCD (round-robin
// dispatch heuristic): one cell is written by one XCD's L2 -> full-line
// writebacks. 4B packed entries halve payload regardless.
__global__ __launch_bounds__(256) void bucket_scatter(const int* __restrict__ src,
                                                      const int* __restrict__ dst,
                                                      int* __restrict__ bcnt,
                                                      int* __restrict__ ebuf) {
    int e = blockIdx.x * 256 + threadIdx.x;
    if (e >= NEDGES) return;
    int slot = blockIdx.x & 7;
    int d = dst[e], s = src[e];
    int cell = (d >> 7) * NSLOT + slot;
    int pos = atomicAdd(&bcnt[cell * 4], 1);
    if (pos < CELLCAP)  // 12-sigma margin; guard keeps corruption impossible
        ebuf[(size_t)cell * CELLCAP + pos] = (s << 7) | (d & 127);
}

// exclusive scan of 782 bucket totals (sum of 8 slot counts each)
__global__ __launch_bounds__(1024) void scan_boff(const int* __restrict__ bcnt,
                                                  int* __restrict__ boff) {
    __shared__ int tmp[1024];
    int t = threadIdx.x;
    int v = 0;
    if (t < NBUCKETS)
#pragma unroll
        for (int s = 0; s < NSLOT; s++) v += min(bcnt[(t * NSLOT + s) * 4], CELLCAP);
    tmp[t] = v;
    __syncthreads();
#pragma unroll
    for (int d = 1; d < 1024; d <<= 1) {
        int u = (t >= d) ? tmp[t - d] : 0;
        __syncthreads();
        tmp[t] += u;
        __syncthreads();
    }
    if (t < NBUCKETS) boff[t] = tmp[t] - v;
}

// one block per bucket: LDS histogram over 128 local nodes, LDS scan, emit
// offs + dst-sorted csr. All global writes land in the bucket's contiguous range.
__global__ __launch_bounds__(256) void bucket_build(const int* __restrict__ bcnt,
                                                    const int* __restrict__ boff,
                                                    const int* __restrict__ ebuf,
                                                    int* __restrict__ csr,
                                                    int* __restrict__ offs) {
    __shared__ int hist[NPB];
    __shared__ int tmp[NPB];
    __shared__ int scnt[NSLOT];
    int b = blockIdx.x, tid = threadIdx.x;
    int nodes0 = b << 7;
    int base = boff[b];
    if (tid < NSLOT) scnt[tid] = min(bcnt[(b * NSLOT + tid) * 4], CELLCAP);
    if (tid < NPB) hist[tid] = 0;
    __syncthreads();
    const int* eb = ebuf + (size_t)b * NSLOT * CELLCAP;
#pragma unroll 1
    for (int s = 0; s < NSLOT; s++) {
        int cnt = scnt[s];
        const int* es = eb + s * CELLCAP;
        for (int i = tid; i < cnt; i += 256) atomicAdd(&hist[es[i] & 127], 1);
    }
    __syncthreads();
    if (tid < NPB) tmp[tid] = hist[tid];
    __syncthreads();
#pragma unroll
    for (int d = 1; d < NPB; d <<= 1) {
        int u = (tid < NPB && tid >= d) ? tmp[tid - d] : 0;
        __syncthreads();
        if (tid < NPB) tmp[tid] += u;
        __syncthreads();
    }
    int nloc = min(NPB, NNODES - nodes0);
    if (tid < NPB) {
        int excl = tmp[tid] - hist[tid];
        hist[tid] = excl;                 // becomes running cursor
        if (tid < nloc) offs[nodes0 + tid] = base + excl;
        if (b == NBUCKETS - 1 && tid == NPB - 1) offs[NNODES] = base + tmp[NPB - 1];
    }
    __syncthreads();
#pragma unroll 1
    for (int s = 0; s < NSLOT; s++) {
        int cnt = scnt[s];
        const int* es = eb + s * CELLCAP;
        for (int i = tid; i < cnt; i += 256) {
            int v = es[i];
            int p = atomicAdd(&hist[v & 127], 1);
            csr[base + p] = v >> 7;
        }
    }
}

// per-graph 1/count via binary search on sorted batch
__device__ inline int lower_bound_i(const int* __restrict__ b, int n, int key) {
    int lo = 0, hi = n;
    while (lo < hi) {
        int m = (lo + hi) >> 1;
        if (b[m] < key) lo = m + 1; else hi = m;
    }
    return lo;
}

__global__ void graph_inv(const int* __restrict__ batch, float* __restrict__ ginv) {
    int g = threadIdx.x;
    if (g >= NGRAPH) return;
    int s = lower_bound_i(batch, NNODES, g);
    int e = lower_bound_i(batch, NNODES, g + 1);
    ginv[g] = 1.0f / (float)max(e - s, 1);
}

// xl = x @ w1_l.T ; xr = x @ w1_r.T + b1
__global__ __launch_bounds__(256) void transform1(const float* __restrict__ x,
                                                  const float* __restrict__ w1l,
                                                  const float* __restrict__ b1,
                                                  const float* __restrict__ w1r,
                                                  float* __restrict__ xl,
                                                  float* __restrict__ xr) {
    __shared__ float wl[CHID * CIN];
    __shared__ float wr[CHID * CIN];
    __shared__ float bs[CHID];
    for (int i = threadIdx.x; i < CHID * CIN; i += 256) { wl[i] = w1l[i]; wr[i] = w1r[i]; }
    if (threadIdx.x < CHID) bs[threadIdx.x] = b1[threadIdx.x];
    __syncthreads();
    int n = blockIdx.x * 256 + threadIdx.x;
    if (n >= NNODES) return;
    float xv[CIN];
    const float4* x4 = (const float4*)(x + (size_t)n * CIN);
#pragma unroll
    for (int q = 0; q < CIN / 4; q++) {
        float4 v = x4[q];
        xv[4*q] = v.x; xv[4*q+1] = v.y; xv[4*q+2] = v.z; xv[4*q+3] = v.w;
    }
#pragma unroll
    for (int o = 0; o < CHID; o++) {
        float aL = 0.f, aR = bs[o];
#pragma unroll
        for (int i = 0; i < CIN; i++) {
            aL = fmaf(wl[o * CIN + i], xv[i], aL);
            aR = fmaf(wr[o * CIN + i], xv[i], aR);
        }
        xl[(size_t)n * CHID + o] = aL;
        xr[(size_t)n * CHID + o] = aR;
    }
}

// layer-1 aggregate + finalize: h[n] = relu(mean_in(xl[src]) + xr[n])
__global__ __launch_bounds__(256) void agg1_fused(const int* __restrict__ offs,
                                                  const int* __restrict__ csr,
                                                  const float* __restrict__ xl,
                                                  const float* __restrict__ xr,
                                                  float* __restrict__ h) {
    int node = blockIdx.x * 16 + (threadIdx.x >> 4);
    int c = threadIdx.x & 15;
    int s0 = offs[node], s1 = offs[node + 1];
    float acc = 0.f;
    int p = s0;
    for (; p + 1 < s1; p += 2) {
        int sA = csr[p], sB = csr[p + 1];
        acc += xl[(size_t)sA * CHID + c];
        acc += xl[(size_t)sB * CHID + c];
    }
    if (p < s1) acc += xl[(size_t)csr[p] * CHID + c];
    float mean = acc / (float)max(s1 - s0, 1);
    h[(size_t)node * CHID + c] = fmaxf(mean + xr[(size_t)node * CHID + c], 0.f);
}

// layer-2 aggregate + output transform + FUSED graph pooling:
// node_out = mean_in(h[src]) @ w2_l.T + b2 + h[n] @ w2_r.T, then
// out[g] += node_out * ginv[g] via block-LDS accumulation (h2 never exists)
__global__ __launch_bounds__(256) void agg2_pool(const int* __restrict__ offs,
                                                 const int* __restrict__ csr,
                                                 const float* __restrict__ h,
                                                 const float* __restrict__ w2l,
                                                 const float* __restrict__ b2,
                                                 const float* __restrict__ w2r,
                                                 const int* __restrict__ batch,
                                                 const float* __restrict__ ginv,
                                                 float* __restrict__ out) {
    __shared__ float wlT[CHID * COUT];      // transposed: conflict-free
    __shared__ float wrT[CHID * COUT];
    __shared__ float bs[COUT];
    __shared__ float mean_s[16 * CHID];
    __shared__ float pool[16 * COUT];
    __shared__ int used[16];
    for (int idx = threadIdx.x; idx < CHID * COUT; idx += 256) {
        int i = idx >> 6, o = idx & 63;
        wlT[idx] = w2l[o * CHID + i];
        wrT[idx] = w2r[o * CHID + i];
    }
    if (threadIdx.x < COUT) bs[threadIdx.x] = b2[threadIdx.x];
    for (int idx = threadIdx.x; idx < 16 * COUT; idx += 256) pool[idx] = 0.f;
    if (threadIdx.x < 16) used[threadIdx.x] = 0;
    __syncthreads();

    int g = threadIdx.x >> 4;
    int c = threadIdx.x & 15;
    int node = blockIdx.x * 16 + g;         // grid exact: 6250*16 = 100000
    int gbase = batch[blockIdx.x * 16];     // sorted batch -> gloc in [0,16)
    int gid = batch[node];
    int gloc = gid - gbase;
    float gw = ginv[gid];
    if (c == 0) used[gloc] = 1;

    int s0 = offs[node], s1 = offs[node + 1];
    float acc = 0.f;
    int p = s0;
    for (; p + 1 < s1; p += 2) {
        int sA = csr[p], sB = csr[p + 1];
        acc += h[(size_t)sA * CHID + c];
        acc += h[(size_t)sB * CHID + c];
    }
    if (p < s1) acc += h[(size_t)csr[p] * CHID + c];
    mean_s[g * CHID + c] = acc / (float)max(s1 - s0, 1);
    __syncthreads();

    float hv[CHID], m[CHID];
    const float4* h4 = (const float4*)(h + (size_t)node * CHID);
#pragma unroll
    for (int q = 0; q < CHID / 4; q++) {
        float4 v = h4[q];
        hv[4*q] = v.x; hv[4*q+1] = v.y; hv[4*q+2] = v.z; hv[4*q+3] = v.w;
    }
#pragma unroll
    for (int i = 0; i < CHID; i++) m[i] = mean_s[g * CHID + i];

#pragma unroll
    for (int k = 0; k < 4; k++) {
        int o = c + 16 * k;
        float s = bs[o];
#pragma unroll
        for (int i = 0; i < CHID; i++) {
            s = fmaf(wlT[i * COUT + o], m[i], s);
            s = fmaf(wrT[i * COUT + o], hv[i], s);
        }
        atomicAdd(&pool[gloc * COUT + o], s * gw);
    }
    __syncthreads();
    for (int idx = threadIdx.x; idx < 16 * COUT; idx += 256) {
        int row = idx >> 6;
        if (used[row]) atomicAdd(&out[(gbase + row) * COUT + (idx & 63)], pool[idx]);
    }
}

extern "C" void kernel_launch(void* const* d_in, const int* in_sizes, int n_in,
                              void* d_out, int out_size, void* d_ws, size_t ws_size,
                              hipStream_t stream) {
    const float* x    = (const float*)d_in[0];
    const int*   ei   = (const int*)d_in[1];   // [2, E] int32
    const int*   batch= (const int*)d_in[2];
    const float* w1l  = (const float*)d_in[3];
    const float* b1   = (const float*)d_in[4];
    const float* w1r  = (const float*)d_in[5];
    const float* w2l  = (const float*)d_in[6];
    const float* b2   = (const float*)d_in[7];
    const float* w2r  = (const float*)d_in[8];
    float* out = (float*)d_out;

    const int* src = ei;
    const int* dst = ei + NEDGES;

    int*   ws_i = (int*)d_ws;
    float* ws_f = (float*)d_ws;
    int*   bcnt = ws_i + OFF_BCNT;
    int*   boff = ws_i + OFF_BOFF;
    float* ginv = ws_f + OFF_GINV;
    int*   offs = ws_i + OFF_OFFS;
    int*   csr  = ws_i + OFF_CSR;
    int*   ebuf = ws_i + OFF_EBUF;
    float* xl   = ws_f + OFF_XL;
    float* xr   = ws_f + OFF_XR;
    float* h    = ws_f + OFF_H;

    hipMemsetAsync(bcnt, 0, 25088 * sizeof(int), stream);
    hipMemsetAsync(out, 0, NGRAPH * COUT * sizeof(float), stream);

    int ebl = (NEDGES + 255) / 256;
    int nbl = (NNODES + 255) / 256;
    int abl = NNODES / 16;      // 6250, exact

    bucket_scatter<<<ebl, 256, 0, stream>>>(src, dst, bcnt, ebuf);
    scan_boff     <<<1, 1024, 0, stream>>>(bcnt, boff);
    bucket_build  <<<NBUCKETS, 256, 0, stream>>>(bcnt, boff, ebuf, csr, offs);
    transform1    <<<nbl, 256, 0, stream>>>(x, w1l, b1, w1r, xl, xr);
    graph_inv     <<<1, 64, 0, stream>>>(batch, ginv);
    agg1_fused    <<<abl, 256, 0, stream>>>(offs, csr, xl, xr, h);
    agg2_pool     <<<abl, 256, 0, stream>>>(offs, csr, h, w2l, b2, w2r, batch, ginv, out);
}